// Round 3
// baseline (1140.410 us; speedup 1.0000x reference)
//
#include <hip/hip_runtime.h>

// ---------------- problem constants ----------------
#define T_TOK 8192      // B*S tokens
#define DDIM  1024
#define NEXP  8
#define FDIM  4096
#define BM    256       // GEMM tile M (slots)
#define BN    128       // GEMM tile N
#define BK    64        // GEMM K-step
#define SLOT_CAP (T_TOK*2 + NEXP*BM)   // 18432 padded (token,expert) slots

using short8  = __attribute__((ext_vector_type(8))) short;   // 8 bf16 (A/B frag)
using floatx4 = __attribute__((ext_vector_type(4))) float;   // C/D frag

__device__ __forceinline__ unsigned short f32_to_bf16(float f) {
    unsigned int u = __float_as_uint(f);
    u = (u + 0x7FFFu + ((u >> 16) & 1u)) >> 16;   // RTNE
    return (unsigned short)u;
}

// ---------------- router: logits -> top2 -> gates + counts ; also x->bf16 ----------------
__global__ void router_kernel(const float* __restrict__ x, const float* __restrict__ gw,
                              int* __restrict__ tk_e, float* __restrict__ tk_g,
                              int* __restrict__ counts, unsigned short* __restrict__ xb) {
    const int wave = threadIdx.x >> 6, lane = threadIdx.x & 63;
    const int t = blockIdx.x * 4 + wave;
    const float* xr = x + (size_t)t * DDIM;
    unsigned short* xbr = xb + (size_t)t * DDIM;
    float acc[8] = {0.f,0.f,0.f,0.f,0.f,0.f,0.f,0.f};
    for (int i = lane; i < DDIM; i += 64) {
        float xv = xr[i];
        xbr[i] = f32_to_bf16(xv);                 // fused fp32->bf16 (coalesced 2B/lane)
        const float4* g4 = (const float4*)(gw + i * NEXP);
        float4 a = g4[0], b = g4[1];
        acc[0] += xv*a.x; acc[1] += xv*a.y; acc[2] += xv*a.z; acc[3] += xv*a.w;
        acc[4] += xv*b.x; acc[5] += xv*b.y; acc[6] += xv*b.z; acc[7] += xv*b.w;
    }
    #pragma unroll
    for (int s = 32; s > 0; s >>= 1)
        #pragma unroll
        for (int e = 0; e < 8; ++e)
            acc[e] += __shfl_xor(acc[e], s, 64);
    if (lane == 0) {
        int e0 = 0; float v0 = acc[0];
        #pragma unroll
        for (int e = 1; e < 8; ++e) if (acc[e] > v0) { v0 = acc[e]; e0 = e; }
        int e1 = -1; float v1 = -1e30f;
        #pragma unroll
        for (int e = 0; e < 8; ++e) if (e != e0 && acc[e] > v1) { v1 = acc[e]; e1 = e; }
        float g0 = 1.0f / (1.0f + expf(v1 - v0));  // renormalized top-2 softmax
        tk_e[t*2] = e0;  tk_e[t*2+1] = e1;
        tk_g[t*2] = g0;  tk_g[t*2+1] = 1.0f - g0;
        atomicAdd(&counts[e0], 1);
        atomicAdd(&counts[e1], 1);
    }
}

// ---------------- scan: padded per-expert offsets (align BM=256) ----------------
__global__ void scan_kernel(const int* __restrict__ counts, int* __restrict__ offsets) {
    if (threadIdx.x == 0 && blockIdx.x == 0) {
        int o = 0;
        for (int e = 0; e < NEXP; ++e) {
            offsets[e] = o;
            o += (counts[e] + BM - 1) & ~(BM - 1);
        }
        offsets[NEXP] = o;
    }
}

// ---------------- scatter: (token,k) -> slot sorted by expert ----------------
__global__ void scatter_kernel(const int* __restrict__ tk_e,
                               const int* __restrict__ offsets, int* __restrict__ cursors,
                               int* __restrict__ perm_token, int* __restrict__ tok2slot) {
    int i = blockIdx.x * 256 + threadIdx.x;
    if (i >= 2 * T_TOK) return;
    int e = tk_e[i];
    int slot = offsets[e] + atomicAdd(&cursors[e], 1);
    perm_token[slot] = i >> 1;
    tok2slot[i] = slot;
}

// ---------------- transpose + fp32->bf16: in [E][R][C] -> out [E][C][R] ----------------
__global__ void transpose_cvt_kernel(const float* __restrict__ in, unsigned short* __restrict__ outp,
                                     int R, int C) {
    const int e = blockIdx.z;
    const float* w = in + (size_t)e * R * C;
    unsigned short* o = outp + (size_t)e * R * C;
    __shared__ float tile[64][65];
    const int l = threadIdx.x & 15, row = threadIdx.x >> 4;   // 16 x 16
    const int c0 = blockIdx.x * 64, r0 = blockIdx.y * 64;
    #pragma unroll
    for (int j = 0; j < 4; ++j) {
        int r = row + j * 16;
        float4 v = *(const float4*)(w + (size_t)(r0 + r) * C + c0 + l * 4);
        tile[r][l*4+0] = v.x; tile[r][l*4+1] = v.y; tile[r][l*4+2] = v.z; tile[r][l*4+3] = v.w;
    }
    __syncthreads();
    #pragma unroll
    for (int j = 0; j < 4; ++j) {
        int c = row + j * 16;
        ushort4 v;
        v.x = f32_to_bf16(tile[l*4+0][c]);
        v.y = f32_to_bf16(tile[l*4+1][c]);
        v.z = f32_to_bf16(tile[l*4+2][c]);
        v.w = f32_to_bf16(tile[l*4+3][c]);
        *(ushort4*)(o + (size_t)(c0 + c) * R + r0 + l * 4) = v;
    }
}

// ============== pipelined GEMM template pieces (T3+T4+T5, ring-3 LDS) ==============
// Geometry: BM=256 x BN=128, BK=64, 512 threads = 8 waves (2M x 4N).
// Per-wave output 128x32 -> acc[8][2] floatx4. 16 MFMA per phase, 2 phases/tile.
// LDS ring of 3 K-tiles: A = 2 halves (128 rows x 64 k) each 16 KiB, B = 1 half.
// 144 KiB total -> 1 block/CU, 2 waves/SIMD (HK regime).
// Stagger/ledger (per-thread loads, 2 per half-tile):
//   t.F1 stages (t+2).Ah0 + (t+2).B  [4 loads]
//   t.F2 stages (t+2).Ah1            [2 loads] + GATE vmcnt(6)
// Gate at t.F2 protects tile t+1 (its 6 loads issued at (t-1).F1/F2); the 6
// newest in flight are tile t+2's -> vmcnt never drains to 0 in the loop (T4).
// Slot safety: (t+2)%3 == (t-1)%3; tile t-1's reads retire before its trailing
// barrier (compiler lgkmcnt before MFMA), one full phase before the overwrite.

#define STAGE_AH(SLOT, H, KOFF) do {                                                        \
    _Pragma("unroll")                                                                       \
    for (int j_ = 0; j_ < 2; ++j_)                                                          \
        __builtin_amdgcn_global_load_lds(                                                   \
            (const __attribute__((address_space(1))) void*)(aP[H][j_] + (KOFF)),            \
            (__attribute__((address_space(3))) void*)((char*)&Ah[SLOT][H][0] + (j_*64 + w*8)*128), \
            16, 0, 0);                                                                      \
} while (0)

#define STAGE_B1(SLOT, KOFF) do {                                                           \
    _Pragma("unroll")                                                                       \
    for (int j_ = 0; j_ < 2; ++j_)                                                          \
        __builtin_amdgcn_global_load_lds(                                                   \
            (const __attribute__((address_space(1))) void*)(bP[j_] + (KOFF)),               \
            (__attribute__((address_space(3))) void*)((char*)&Bs[SLOT][0] + (j_*64 + w*8)*128), \
            16, 0, 0);                                                                      \
} while (0)

#define LOAD_A4(DST, SLOT, IMB) do {                                                        \
    const char* ab_ = (const char*)&Ah[SLOT][wm][0];                                        \
    _Pragma("unroll")                                                                       \
    for (int i_ = 0; i_ < 4; ++i_)                                                          \
        _Pragma("unroll")                                                                   \
        for (int kh_ = 0; kh_ < 2; ++kh_)                                                   \
            DST[i_][kh_] = *(const short8*)(ab_ + (((IMB)+i_)*16 + l15)*128                 \
                                                + (((kh_*4 + quad) ^ l7) << 4));            \
} while (0)

#define LOAD_B2(SLOT) do {                                                                  \
    const char* bb_ = (const char*)&Bs[SLOT][0];                                            \
    _Pragma("unroll")                                                                       \
    for (int in_ = 0; in_ < 2; ++in_)                                                       \
        _Pragma("unroll")                                                                   \
        for (int kh_ = 0; kh_ < 2; ++kh_)                                                   \
            bf[in_][kh_] = *(const short8*)(bb_ + (wn*32 + in_*16 + l15)*128                \
                                                + (((kh_*4 + quad) ^ l7) << 4));            \
} while (0)

#define MFMA16(AF, IMB) do {                                                                \
    _Pragma("unroll")                                                                       \
    for (int i_ = 0; i_ < 4; ++i_)                                                          \
        _Pragma("unroll")                                                                   \
        for (int in_ = 0; in_ < 2; ++in_)                                                   \
            _Pragma("unroll")                                                               \
            for (int kh_ = 0; kh_ < 2; ++kh_)                                               \
                acc[(IMB)+i_][in_] = __builtin_amdgcn_mfma_f32_16x16x32_bf16(               \
                    AF[i_][kh_], bf[in_][kh_], acc[(IMB)+i_][in_], 0, 0, 0);                \
} while (0)

#define GEMM_MAIN_LOOP(NT) do {                                                             \
    STAGE_AH(0, 0, 0); STAGE_AH(0, 1, 0); STAGE_B1(0, 0);                                   \
    STAGE_AH(1, 0, BK); STAGE_AH(1, 1, BK); STAGE_B1(1, BK);                                \
    asm volatile("s_waitcnt vmcnt(6)" ::: "memory");                                        \
    __builtin_amdgcn_s_barrier();                                                           \
    int s0_ = 0, s1_ = 1, s2_ = 2;                                                          \
    _Pragma("unroll 1")                                                                     \
    for (int t_ = 0; t_ < (NT); ++t_) {                                                     \
        const int koff_ = (t_ + 2) * BK;                                                    \
        short8 af[4][2], bf[2][2];                                                          \
        /* F1 */                                                                            \
        LOAD_A4(af, s0_, 0);                                                                \
        LOAD_B2(s0_);                                                                       \
        STAGE_AH(s2_, 0, koff_);                                                            \
        STAGE_B1(s2_, koff_);                                                               \
        asm volatile("" ::: "memory");                                                      \
        __builtin_amdgcn_s_barrier();                                                       \
        __builtin_amdgcn_s_setprio(1);                                                      \
        MFMA16(af, 0);                                                                      \
        __builtin_amdgcn_s_setprio(0);                                                      \
        asm volatile("" ::: "memory");                                                      \
        __builtin_amdgcn_s_barrier();                                                       \
        /* F2 */                                                                            \
        LOAD_A4(af, s0_, 4);                                                                \
        STAGE_AH(s2_, 1, koff_);                                                            \
        asm volatile("s_waitcnt vmcnt(6)" ::: "memory");                                    \
        __builtin_amdgcn_s_barrier();                                                       \
        __builtin_amdgcn_s_setprio(1);                                                      \
        MFMA16(af, 4);                                                                      \
        __builtin_amdgcn_s_setprio(0);                                                      \
        asm volatile("" ::: "memory");                                                      \
        __builtin_amdgcn_s_barrier();                                                       \
        int tmp_ = s0_; s0_ = s1_; s1_ = s2_; s2_ = tmp_;                                   \
    }                                                                                       \
    asm volatile("s_waitcnt vmcnt(0)" ::: "memory"); /* drain tail prefetch before LDS dealloc */ \
} while (0)

// ---------------- GEMM1: h = gelu(x[perm] @ w1[e] + b1[e]), bf16 out ----------------
__global__ __launch_bounds__(512, 2) void gemm1_kernel(
    const unsigned short* __restrict__ xb, const unsigned short* __restrict__ w1T,
    const float* __restrict__ b1, const int* __restrict__ perm_token,
    const int* __restrict__ offsets, unsigned short* __restrict__ h) {
    __shared__ __align__(16) unsigned short Ah[3][2][128 * 64];   // 96 KiB
    __shared__ __align__(16) unsigned short Bs[3][128 * 64];      // 48 KiB
    // XCD-grouped map: p%8 == m%8 -> all 32 N-blocks of an M-tile on one XCD
    const int p  = blockIdx.x;
    const int mt = ((p >> 8) << 3) | (p & 7);      // 0..71
    const int nt = (p >> 3) & 31;                  // 0..31
    const int row0 = mt * BM;
    if (row0 >= offsets[NEXP]) return;
    const int n0 = nt * BN;
    int e = 0;
    while (e < NEXP - 1 && offsets[e + 1] <= row0) ++e;
    const int w = threadIdx.x >> 6, lane = threadIdx.x & 63;
    const int srow = lane >> 3;
    const int scol = (lane & 7) ^ srow;            // XOR-swizzle on global side, LDS linear
    const unsigned short* aP[2][2];
    const unsigned short* bP[2];
    #pragma unroll
    for (int hh = 0; hh < 2; ++hh)
        #pragma unroll
        for (int j = 0; j < 2; ++j) {
            int arow = row0 + hh * 128 + j * 64 + w * 8 + srow;
            int tok = perm_token[arow];
            aP[hh][j] = xb + (size_t)tok * DDIM + scol * 8;
        }
    #pragma unroll
    for (int j = 0; j < 2; ++j) {
        int brow = n0 + j * 64 + w * 8 + srow;
        bP[j] = w1T + ((size_t)e * FDIM + brow) * DDIM + scol * 8;
    }
    const int wm = w >> 2, wn = w & 3;
    const int l15 = lane & 15, quad = lane >> 4, l7 = lane & 7;
    floatx4 acc[8][2];
    #pragma unroll
    for (int im = 0; im < 8; ++im)
        #pragma unroll
        for (int in_ = 0; in_ < 2; ++in_)
            acc[im][in_] = (floatx4){0.f, 0.f, 0.f, 0.f};

    GEMM_MAIN_LOOP(DDIM / BK);

    // epilogue: bias + tanh-gelu -> bf16 h
    float bias[2];
    #pragma unroll
    for (int in_ = 0; in_ < 2; ++in_) bias[in_] = b1[e * FDIM + n0 + wn * 32 + in_ * 16 + l15];
    #pragma unroll
    for (int im = 0; im < 8; ++im) {
        int mrow = row0 + wm * 128 + im * 16 + quad * 4;
        #pragma unroll
        for (int r = 0; r < 4; ++r) {
            #pragma unroll
            for (int in_ = 0; in_ < 2; ++in_) {
                int n = n0 + wn * 32 + in_ * 16 + l15;
                float z = acc[im][in_][r] + bias[in_];
                float u = __expf(1.5957691216057308f * (z + 0.044715f * z * z * z));
                float t = 1.0f - __fdividef(2.0f, u + 1.0f);     // tanh
                float g = 0.5f * z * (1.0f + t);
                h[(size_t)(mrow + r) * FDIM + n] = f32_to_bf16(g);
            }
        }
    }
}

// ---------------- GEMM2: y[slot] = h[slot] @ w2[e] + b2[e]  (fp32, no gate) ----------------
__global__ __launch_bounds__(512, 2) void gemm2_kernel(
    const unsigned short* __restrict__ h, const unsigned short* __restrict__ w2T,
    const float* __restrict__ b2, const int* __restrict__ offsets,
    float* __restrict__ y) {
    __shared__ __align__(16) unsigned short Ah[3][2][128 * 64];
    __shared__ __align__(16) unsigned short Bs[3][128 * 64];
    const int p  = blockIdx.x;
    const int mt = ((p >> 6) << 3) | (p & 7);      // 0..71
    const int nt = (p >> 3) & 7;                   // 0..7
    const int row0 = mt * BM;
    if (row0 >= offsets[NEXP]) return;
    const int n0 = nt * BN;
    int e = 0;
    while (e < NEXP - 1 && offsets[e + 1] <= row0) ++e;
    const int w = threadIdx.x >> 6, lane = threadIdx.x & 63;
    const int srow = lane >> 3;
    const int scol = (lane & 7) ^ srow;
    const unsigned short* aP[2][2];
    const unsigned short* bP[2];
    #pragma unroll
    for (int hh = 0; hh < 2; ++hh)
        #pragma unroll
        for (int j = 0; j < 2; ++j) {
            int arow = row0 + hh * 128 + j * 64 + w * 8 + srow;
            aP[hh][j] = h + (size_t)arow * FDIM + scol * 8;
        }
    #pragma unroll
    for (int j = 0; j < 2; ++j) {
        int brow = n0 + j * 64 + w * 8 + srow;
        bP[j] = w2T + ((size_t)e * DDIM + brow) * FDIM + scol * 8;
    }
    const int wm = w >> 2, wn = w & 3;
    const int l15 = lane & 15, quad = lane >> 4, l7 = lane & 7;
    floatx4 acc[8][2];
    #pragma unroll
    for (int im = 0; im < 8; ++im)
        #pragma unroll
        for (int in_ = 0; in_ < 2; ++in_)
            acc[im][in_] = (floatx4){0.f, 0.f, 0.f, 0.f};

    GEMM_MAIN_LOOP(FDIM / BK);

    // epilogue: bias, fp32 stores
    float bias[2];
    #pragma unroll
    for (int in_ = 0; in_ < 2; ++in_) bias[in_] = b2[e * DDIM + n0 + wn * 32 + in_ * 16 + l15];
    #pragma unroll
    for (int im = 0; im < 8; ++im) {
        int mrow = row0 + wm * 128 + im * 16 + quad * 4;
        #pragma unroll
        for (int r = 0; r < 4; ++r) {
            #pragma unroll
            for (int in_ = 0; in_ < 2; ++in_) {
                int n = n0 + wn * 32 + in_ * 16 + l15;
                y[(size_t)(mrow + r) * DDIM + n] = acc[im][in_][r] + bias[in_];
            }
        }
    }
}

// ---------------- combine: out[t] = g0*y[s0] + g1*y[s1] ----------------
__global__ void combine_kernel(const float* __restrict__ y, const int* __restrict__ tok2slot,
                               const float* __restrict__ tk_g, float* __restrict__ out) {
    const int t = blockIdx.x;
    const int s0 = tok2slot[2 * t], s1 = tok2slot[2 * t + 1];
    const float g0 = tk_g[2 * t], g1 = tk_g[2 * t + 1];
    float4 a = ((const float4*)(y + (size_t)s0 * DDIM))[threadIdx.x];
    float4 b = ((const float4*)(y + (size_t)s1 * DDIM))[threadIdx.x];
    float4 o;
    o.x = g0 * a.x + g1 * b.x;  o.y = g0 * a.y + g1 * b.y;
    o.z = g0 * a.z + g1 * b.z;  o.w = g0 * a.w + g1 * b.w;
    ((float4*)(out + (size_t)t * DDIM))[threadIdx.x] = o;
}

// ---------------- launch ----------------
extern "C" void kernel_launch(void* const* d_in, const int* in_sizes, int n_in,
                              void* d_out, int out_size, void* d_ws, size_t ws_size,
                              hipStream_t stream) {
    (void)in_sizes; (void)n_in; (void)ws_size; (void)out_size;
    const float* x  = (const float*)d_in[0];
    const float* gw = (const float*)d_in[1];
    const float* w1 = (const float*)d_in[2];
    const float* b1 = (const float*)d_in[3];
    const float* w2 = (const float*)d_in[4];
    const float* b2 = (const float*)d_in[5];
    float* out = (float*)d_out;

    char* ws = (char*)d_ws;
    size_t off = 0;
    unsigned short* xb  = (unsigned short*)(ws + off); off += (size_t)T_TOK * DDIM * 2;       // 16 MiB
    unsigned short* w1T = (unsigned short*)(ws + off); off += (size_t)NEXP * DDIM * FDIM * 2; // 64 MiB
    unsigned short* w2T = (unsigned short*)(ws + off); off += (size_t)NEXP * DDIM * FDIM * 2; // 64 MiB
    unsigned short* h   = (unsigned short*)(ws + off); off += (size_t)SLOT_CAP * FDIM * 2;    // 144 MiB
    // y (fp32, 72 MiB) overlays xb+w1T (80 MiB): both dead after gemm1
    float* y = (float*)d_ws;
    int*   meta       = (int*)(ws + off);
    int*   perm_token = meta;                          // SLOT_CAP  (memset 0: pad slots)
    int*   counts     = meta + SLOT_CAP;               // 8         (memset 0)
    int*   cursors    = counts + NEXP;                 // 8         (memset 0)
    int*   offsets    = cursors + NEXP;                // 9
    int*   tk_e       = offsets + NEXP + 1;            // 2T
    float* tk_g       = (float*)(tk_e + 2 * T_TOK);    // 2T
    int*   tok2slot   = (int*)(tk_g + 2 * T_TOK);      // 2T

    hipMemsetAsync(meta, 0, (size_t)(SLOT_CAP + 2 * NEXP) * 4, stream);

    router_kernel<<<T_TOK / 4, 256, 0, stream>>>(x, gw, tk_e, tk_g, counts, xb);
    scan_kernel<<<1, 64, 0, stream>>>(counts, offsets);
    scatter_kernel<<<(2 * T_TOK) / 256, 256, 0, stream>>>(tk_e, offsets, cursors,
                                                          perm_token, tok2slot);
    dim3 gt1(FDIM / 64, DDIM / 64, NEXP);
    transpose_cvt_kernel<<<gt1, 256, 0, stream>>>(w1, w1T, DDIM, FDIM);
    dim3 gt2(DDIM / 64, FDIM / 64, NEXP);
    transpose_cvt_kernel<<<gt2, 256, 0, stream>>>(w2, w2T, FDIM, DDIM);

    // 1-D grids with XCD-grouped mapping decoded in-kernel
    gemm1_kernel<<<(SLOT_CAP / BM) * (FDIM / BN), 512, 0, stream>>>(xb, w1T, b1, perm_token, offsets, h);
    gemm2_kernel<<<(SLOT_CAP / BM) * (DDIM / BN), 512, 0, stream>>>(h, w2T, b2, offsets, y);
    combine_kernel<<<T_TOK, 256, 0, stream>>>(y, tok2slot, tk_g, out);
}

// Round 4
// 742.028 us; speedup vs baseline: 1.5369x; 1.5369x over previous
//
#include <hip/hip_runtime.h>

// ---------------- problem constants ----------------
#define T_TOK 8192      // B*S tokens
#define DDIM  1024
#define NEXP  8
#define FDIM  4096
#define BM    128       // GEMM tile M=N
#define BK    64        // GEMM K-step
#define SLOT_CAP (T_TOK*2 + NEXP*BM)   // 17408 padded (token,expert) slots

using short8  = __attribute__((ext_vector_type(8))) short;   // 8 bf16 (A/B frag)
using floatx4 = __attribute__((ext_vector_type(4))) float;   // C/D frag

__device__ __forceinline__ unsigned short f32_to_bf16(float f) {
    unsigned int u = __float_as_uint(f);
    u = (u + 0x7FFFu + ((u >> 16) & 1u)) >> 16;   // RTNE
    return (unsigned short)u;
}

// ---------------- router: logits -> top2 -> gates ; also x->bf16 ----------------
__global__ void router_kernel(const float* __restrict__ x, const float* __restrict__ gw,
                              int* __restrict__ tk_e, float* __restrict__ tk_g,
                              unsigned short* __restrict__ xb) {
    const int wave = threadIdx.x >> 6, lane = threadIdx.x & 63;
    const int t = blockIdx.x * 4 + wave;
    const float* xr = x + (size_t)t * DDIM;
    unsigned short* xbr = xb + (size_t)t * DDIM;
    float acc[8] = {0.f,0.f,0.f,0.f,0.f,0.f,0.f,0.f};
    for (int i = lane; i < DDIM; i += 64) {
        float xv = xr[i];
        xbr[i] = f32_to_bf16(xv);                 // fused fp32->bf16 (coalesced 2B/lane)
        const float4* g4 = (const float4*)(gw + i * NEXP);
        float4 a = g4[0], b = g4[1];
        acc[0] += xv*a.x; acc[1] += xv*a.y; acc[2] += xv*a.z; acc[3] += xv*a.w;
        acc[4] += xv*b.x; acc[5] += xv*b.y; acc[6] += xv*b.z; acc[7] += xv*b.w;
    }
    #pragma unroll
    for (int s = 32; s > 0; s >>= 1)
        #pragma unroll
        for (int e = 0; e < 8; ++e)
            acc[e] += __shfl_xor(acc[e], s, 64);
    if (lane == 0) {
        int e0 = 0; float v0 = acc[0];
        #pragma unroll
        for (int e = 1; e < 8; ++e) if (acc[e] > v0) { v0 = acc[e]; e0 = e; }
        int e1 = -1; float v1 = -1e30f;
        #pragma unroll
        for (int e = 0; e < 8; ++e) if (e != e0 && acc[e] > v1) { v1 = acc[e]; e1 = e; }
        float g0 = 1.0f / (1.0f + expf(v1 - v0));  // renormalized top-2 softmax
        tk_e[t*2] = e0;  tk_e[t*2+1] = e1;
        tk_g[t*2] = g0;  tk_g[t*2+1] = 1.0f - g0;
    }
}

// ---------------- fused count + scan + scatter + pad-fill (single block) ----------------
// Replaces: memset(meta) + scan_kernel + scatter_kernel and all contended GLOBAL
// atomics (LDS histogram/cursors instead). 2 passes over tk_e (64 KB each).
__global__ void sortscatter_kernel(const int* __restrict__ tk_e, int* __restrict__ offsets,
                                   int* __restrict__ perm_token, int* __restrict__ tok2slot) {
    __shared__ int cnt[NEXP];
    __shared__ int off_s[NEXP + 1];
    __shared__ int cur[NEXP];
    const int tid = threadIdx.x;
    if (tid < NEXP) cnt[tid] = 0;
    __syncthreads();
    for (int i = tid; i < 2 * T_TOK; i += 1024)
        atomicAdd(&cnt[tk_e[i]], 1);
    __syncthreads();
    if (tid == 0) {
        int o = 0;
        for (int e = 0; e < NEXP; ++e) {
            off_s[e] = o; cur[e] = 0;
            o += (cnt[e] + BM - 1) & ~(BM - 1);
        }
        off_s[NEXP] = o;
    }
    __syncthreads();
    if (tid <= NEXP) offsets[tid] = off_s[tid];
    for (int i = tid; i < 2 * T_TOK; i += 1024) {
        int e = tk_e[i];
        int slot = off_s[e] + atomicAdd(&cur[e], 1);
        perm_token[slot] = i >> 1;
        tok2slot[i] = slot;
    }
    __syncthreads();
    // pad slots -> token 0 (their outputs are never gathered by combine)
    #pragma unroll
    for (int e = 0; e < NEXP; ++e) {
        int base = off_s[e] + cnt[e];
        int pad  = off_s[e + 1] - base;
        for (int i = tid; i < pad; i += 1024) perm_token[base + i] = 0;
    }
}

// ---------------- fused transpose + fp32->bf16 for BOTH weights ----------------
// z<8: w1 expert z (R=DDIM,C=FDIM); z>=8: w2 expert z-8 (R=FDIM,C=DDIM).
// 64x64 tiles, float4 loads, ushort4 stores, pad-65 LDS (2-way conflicts only).
__global__ void transpose_cvt2_kernel(const float* __restrict__ w1, const float* __restrict__ w2,
                                      unsigned short* __restrict__ w1T, unsigned short* __restrict__ w2T) {
    const int z = blockIdx.y;
    const bool is1 = z < NEXP;
    const int e = is1 ? z : z - NEXP;
    const int C = is1 ? FDIM : DDIM;
    const int cshift = is1 ? 6 : 4;                // tiles along C = C/64
    const int R = is1 ? DDIM : FDIM;
    const float* w = (is1 ? w1 : w2) + (size_t)e * DDIM * FDIM;
    unsigned short* o = (is1 ? w1T : w2T) + (size_t)e * DDIM * FDIM;
    const int t = blockIdx.x;                      // 1024 tiles per expert
    const int c0 = (t & ((C >> 6) - 1)) * 64, r0 = (t >> cshift) * 64;
    __shared__ float tile[64][65];
    const int l = threadIdx.x & 15, row = threadIdx.x >> 4;   // 16 x 16
    #pragma unroll
    for (int j = 0; j < 4; ++j) {
        int r = row + j * 16;
        float4 v = *(const float4*)(w + (size_t)(r0 + r) * C + c0 + l * 4);
        tile[r][l*4+0] = v.x; tile[r][l*4+1] = v.y; tile[r][l*4+2] = v.z; tile[r][l*4+3] = v.w;
    }
    __syncthreads();
    #pragma unroll
    for (int j = 0; j < 4; ++j) {
        int c = row + j * 16;
        ushort4 v;
        v.x = f32_to_bf16(tile[l*4+0][c]);
        v.y = f32_to_bf16(tile[l*4+1][c]);
        v.z = f32_to_bf16(tile[l*4+2][c]);
        v.w = f32_to_bf16(tile[l*4+3][c]);
        *(ushort4*)(o + (size_t)(c0 + c) * R + r0 + l * 4) = v;
    }
}

// ---------------- staging macro (single buffer, m97 structure) ----------------
#define STAGE(AS, BS, KOFF) do {                                                            \
    _Pragma("unroll")                                                                       \
    for (int r = 0; r < 4; ++r) {                                                           \
        __builtin_amdgcn_global_load_lds(                                                   \
            (const __attribute__((address_space(1))) void*)(aptr[r] + (KOFF)),              \
            (__attribute__((address_space(3))) void*)((char*)(AS) + (r * 32 + wave * 8) * 128), \
            16, 0, 0);                                                                      \
        __builtin_amdgcn_global_load_lds(                                                   \
            (const __attribute__((address_space(1))) void*)(bptr[r] + (KOFF)),              \
            (__attribute__((address_space(3))) void*)((char*)(BS) + (r * 32 + wave * 8) * 128), \
            16, 0, 0);                                                                      \
    } } while (0)

#define COMPUTE(AS, BS) do {                                                                \
    _Pragma("unroll")                                                                       \
    for (int kh = 0; kh < 2; ++kh) {                                                        \
        short8 af[4], bfr[4];                                                               \
        _Pragma("unroll")                                                                   \
        for (int im = 0; im < 4; ++im) {                                                    \
            int m = wm * 64 + im * 16 + l15;                                                \
            af[im] = *(const short8*)((const char*)(AS) + m * 128 + (((kh * 4 + quad) ^ l7) << 4)); \
        }                                                                                   \
        _Pragma("unroll")                                                                   \
        for (int in = 0; in < 4; ++in) {                                                    \
            int n = wn * 64 + in * 16 + l15;                                                \
            bfr[in] = *(const short8*)((const char*)(BS) + n * 128 + (((kh * 4 + quad) ^ l7) << 4)); \
        }                                                                                   \
        _Pragma("unroll")                                                                   \
        for (int im = 0; im < 4; ++im)                                                      \
            _Pragma("unroll")                                                               \
            for (int in = 0; in < 4; ++in)                                                  \
                acc[im][in] = __builtin_amdgcn_mfma_f32_16x16x32_bf16(af[im], bfr[in], acc[im][in], 0, 0, 0); \
    } } while (0)

// ---------------- GEMM1: h = gelu(x[perm] @ w1[e] + b1[e]), bf16 out ----------------
// Round-2 proven structure (single 32 KiB LDS, 2-barrier K-step, bounds (256,3)).
// Grid: 1-D XCD-grouped — all 32 N-blocks of an M-tile share p%8 (same XCD) so
// the A-panel is fetched once per XCD (T1).
__global__ __launch_bounds__(256, 3) void gemm1_kernel(
    const unsigned short* __restrict__ xb, const unsigned short* __restrict__ w1T,
    const float* __restrict__ b1, const int* __restrict__ perm_token,
    const int* __restrict__ offsets, unsigned short* __restrict__ h) {
    __shared__ __align__(16) unsigned short As[BM * BK];
    __shared__ __align__(16) unsigned short Bs[BM * BK];
    const int p = blockIdx.x;
    const int q = p >> 3;
    const int nt = q & 31;                          // 32 N-tiles
    const int mt = ((q >> 5) << 3) | (p & 7);       // 136 M-tiles, grouped by XCD
    const int row0 = mt * BM;
    if (row0 >= offsets[NEXP]) return;
    const int n0 = nt * BM;
    int e = 0;
    while (e < NEXP - 1 && offsets[e + 1] <= row0) ++e;
    const int lane = threadIdx.x & 63, wave = threadIdx.x >> 6;
    const int srow = lane >> 3;
    const int scol = (lane & 7) ^ srow;        // XOR-swizzled 16B block (global side)
    const unsigned short* aptr[4];
    const unsigned short* bptr[4];
    #pragma unroll
    for (int r = 0; r < 4; ++r) {
        int arow = r * 32 + wave * 8 + srow;
        int tok = perm_token[row0 + arow];
        aptr[r] = xb + (size_t)tok * DDIM + scol * 8;
        int brow = n0 + r * 32 + wave * 8 + srow;
        bptr[r] = w1T + ((size_t)e * FDIM + brow) * DDIM + scol * 8;
    }
    const int wm = wave >> 1, wn = wave & 1;
    const int l15 = lane & 15, quad = lane >> 4, l7 = lane & 7;
    floatx4 acc[4][4];
    #pragma unroll
    for (int im = 0; im < 4; ++im)
        #pragma unroll
        for (int in = 0; in < 4; ++in)
            acc[im][in] = (floatx4){0.f, 0.f, 0.f, 0.f};

    #pragma unroll 1
    for (int kk = 0; kk < DDIM; kk += BK) {
        __syncthreads();                          // prev compute done; LDS free
        STAGE(As, Bs, kk);
        asm volatile("s_waitcnt vmcnt(0)" ::: "memory");
        __syncthreads();                          // staged tile visible to all waves
        COMPUTE(As, Bs);
    }
    // epilogue: bias + tanh-gelu -> bf16 h (n-fastest store order for write combine)
    #pragma unroll
    for (int im = 0; im < 4; ++im) {
        int mbase = row0 + wm * 64 + im * 16 + quad * 4;
        #pragma unroll
        for (int r = 0; r < 4; ++r) {
            #pragma unroll
            for (int in = 0; in < 4; ++in) {
                int n = n0 + wn * 64 + in * 16 + l15;
                float z = acc[im][in][r] + b1[e * FDIM + n];
                float u = __expf(1.5957691216057308f * (z + 0.044715f * z * z * z));
                float t = 1.0f - __fdividef(2.0f, u + 1.0f);     // tanh
                float g = 0.5f * z * (1.0f + t);
                h[(size_t)(mbase + r) * FDIM + n] = f32_to_bf16(g);
            }
        }
    }
}

// ---------------- GEMM2: y[slot] = h[slot] @ w2[e] + b2[e]  (fp32, no gate) ----------------
__global__ __launch_bounds__(256, 3) void gemm2_kernel(
    const unsigned short* __restrict__ h, const unsigned short* __restrict__ w2T,
    const float* __restrict__ b2, const int* __restrict__ offsets,
    float* __restrict__ y) {
    __shared__ __align__(16) unsigned short As[BM * BK];
    __shared__ __align__(16) unsigned short Bs[BM * BK];
    const int p = blockIdx.x;
    const int q = p >> 3;
    const int nt = q & 7;                           // 8 N-tiles
    const int mt = ((q >> 3) << 3) | (p & 7);       // 136 M-tiles, grouped by XCD
    const int row0 = mt * BM;
    if (row0 >= offsets[NEXP]) return;
    const int n0 = nt * BM;
    int e = 0;
    while (e < NEXP - 1 && offsets[e + 1] <= row0) ++e;
    const int lane = threadIdx.x & 63, wave = threadIdx.x >> 6;
    const int srow = lane >> 3;
    const int scol = (lane & 7) ^ srow;
    const unsigned short* aptr[4];
    const unsigned short* bptr[4];
    #pragma unroll
    for (int r = 0; r < 4; ++r) {
        int arow = r * 32 + wave * 8 + srow;
        aptr[r] = h + (size_t)(row0 + arow) * FDIM + scol * 8;
        int brow = n0 + r * 32 + wave * 8 + srow;
        bptr[r] = w2T + ((size_t)e * DDIM + brow) * FDIM + scol * 8;
    }
    const int wm = wave >> 1, wn = wave & 1;
    const int l15 = lane & 15, quad = lane >> 4, l7 = lane & 7;
    floatx4 acc[4][4];
    #pragma unroll
    for (int im = 0; im < 4; ++im)
        #pragma unroll
        for (int in = 0; in < 4; ++in)
            acc[im][in] = (floatx4){0.f, 0.f, 0.f, 0.f};

    #pragma unroll 1
    for (int kk = 0; kk < FDIM; kk += BK) {
        __syncthreads();
        STAGE(As, Bs, kk);
        asm volatile("s_waitcnt vmcnt(0)" ::: "memory");
        __syncthreads();
        COMPUTE(As, Bs);
    }
    // epilogue: bias, coalesced fp32 stores per slot (quad rows -> 64B lines)
    #pragma unroll
    for (int im = 0; im < 4; ++im) {
        int mbase = row0 + wm * 64 + im * 16 + quad * 4;
        #pragma unroll
        for (int r = 0; r < 4; ++r) {
            #pragma unroll
            for (int in = 0; in < 4; ++in) {
                int n = n0 + wn * 64 + in * 16 + l15;
                y[(size_t)(mbase + r) * DDIM + n] = acc[im][in][r] + b2[e * DDIM + n];
            }
        }
    }
}

// ---------------- combine: out[t] = g0*y[s0] + g1*y[s1] ----------------
__global__ void combine_kernel(const float* __restrict__ y, const int* __restrict__ tok2slot,
                               const float* __restrict__ tk_g, float* __restrict__ out) {
    const int t = blockIdx.x;
    const int s0 = tok2slot[2 * t], s1 = tok2slot[2 * t + 1];
    const float g0 = tk_g[2 * t], g1 = tk_g[2 * t + 1];
    float4 a = ((const float4*)(y + (size_t)s0 * DDIM))[threadIdx.x];
    float4 b = ((const float4*)(y + (size_t)s1 * DDIM))[threadIdx.x];
    float4 o;
    o.x = g0 * a.x + g1 * b.x;  o.y = g0 * a.y + g1 * b.y;
    o.z = g0 * a.z + g1 * b.z;  o.w = g0 * a.w + g1 * b.w;
    ((float4*)(out + (size_t)t * DDIM))[threadIdx.x] = o;
}

// ---------------- launch ----------------
extern "C" void kernel_launch(void* const* d_in, const int* in_sizes, int n_in,
                              void* d_out, int out_size, void* d_ws, size_t ws_size,
                              hipStream_t stream) {
    (void)in_sizes; (void)n_in; (void)ws_size; (void)out_size;
    const float* x  = (const float*)d_in[0];
    const float* gw = (const float*)d_in[1];
    const float* w1 = (const float*)d_in[2];
    const float* b1 = (const float*)d_in[3];
    const float* w2 = (const float*)d_in[4];
    const float* b2 = (const float*)d_in[5];
    float* out = (float*)d_out;

    char* ws = (char*)d_ws;
    size_t off = 0;
    unsigned short* xb  = (unsigned short*)(ws + off); off += (size_t)T_TOK * DDIM * 2;       // 16 MiB
    unsigned short* w1T = (unsigned short*)(ws + off); off += (size_t)NEXP * DDIM * FDIM * 2; // 64 MiB
    unsigned short* w2T = (unsigned short*)(ws + off); off += (size_t)NEXP * DDIM * FDIM * 2; // 64 MiB
    unsigned short* h   = (unsigned short*)(ws + off); off += (size_t)SLOT_CAP * FDIM * 2;    // 136 MiB
    // y (fp32, 68 MiB) overlays xb+w1T: both dead once gemm1 finished; gemm2/combine only
    float* y = (float*)d_ws;
    int*   meta       = (int*)(ws + off);
    int*   perm_token = meta;                          // SLOT_CAP (pads filled by sortscatter)
    int*   offsets    = meta + SLOT_CAP;               // 9
    int*   tk_e       = offsets + NEXP + 1;            // 2T
    float* tk_g       = (float*)(tk_e + 2 * T_TOK);    // 2T
    int*   tok2slot   = (int*)(tk_g + 2 * T_TOK);      // 2T

    router_kernel<<<T_TOK / 4, 256, 0, stream>>>(x, gw, tk_e, tk_g, xb);
    sortscatter_kernel<<<1, 1024, 0, stream>>>(tk_e, offsets, perm_token, tok2slot);
    dim3 gt(1024, 2 * NEXP);
    transpose_cvt2_kernel<<<gt, 256, 0, stream>>>(w1, w2, w1T, w2T);

    // XCD-grouped 1-D grids (decode in-kernel)
    gemm1_kernel<<<(SLOT_CAP / BM) * (FDIM / BM), 256, 0, stream>>>(xb, w1T, b1, perm_token, offsets, h);
    gemm2_kernel<<<(SLOT_CAP / BM) * (DDIM / BM), 256, 0, stream>>>(h, w2T, b2, offsets, y);
    combine_kernel<<<T_TOK, 256, 0, stream>>>(y, tok2slot, tk_g, out);
}